// Round 3
// baseline (170.785 us; speedup 1.0000x reference)
//
#include <hip/hip_runtime.h>
#include <math.h>

#define SIGMA_BOOST 2.0f
#define EPSILON 1e-6f

// native clang vector type — required for __builtin_nontemporal_load/store
typedef float vfloat4 __attribute__((ext_vector_type(4)));

// ---------------------------------------------------------------------------
// Pre-pass: per-t parameters -> float4 {mean_row, mean_col, sigma, pvalue}
//   mean  = sigmoid(pmean) * (N-1)
//   sigma = (softplus(psigma + SIGMA_BOOST) + EPS) * N
// ---------------------------------------------------------------------------
__global__ void params_kernel(const float2* __restrict__ pmeans,
                              const float* __restrict__ psigmas,
                              const float* __restrict__ pvalues,
                              float4* __restrict__ params, int N) {
    int t = blockIdx.x * blockDim.x + threadIdx.x;
    if (t >= N) return;
    float2 pm = pmeans[t];
    float scale = (float)(N - 1);
    float m0 = __fmul_rn(__fdiv_rn(1.0f, __fadd_rn(1.0f, expf(-pm.x))), scale);
    float m1 = __fmul_rn(__fdiv_rn(1.0f, __fadd_rn(1.0f, expf(-pm.y))), scale);
    float z  = __fadd_rn(psigmas[t], SIGMA_BOOST);
    float sp = __fadd_rn(fmaxf(z, 0.0f), log1pf(expf(-fabsf(z))));
    float sg = __fmul_rn(__fadd_rn(sp, EPSILON), (float)N);
    params[t] = make_float4(m0, m1, sg, pvalues[t]);
}

// ---------------------------------------------------------------------------
// STAGED contract kernel (this round's change). One block per batch row.
// LDS = 128 KB: ly[N] accumulator + lx[N] copy of the x-row.
// Rationale: the random per-lane gathers xb[col] touch ~64 distinct cache
// lines per wave instruction -> ~540 MB of sector traffic (16x amplification
// of the 32 MB of x). Cold-cache (timed) runs pay that from HBM (~85 us).
// Staging x in LDS makes x traffic exactly 32 MB coalesced; gathers become
// ds_read_b32 (~6 cyc, random 2-way conflicts ~ free).
// 1 block/CU (LDS-capped, 16 waves); 8 t's per loop step keeps 4 independent
// 16B noise loads in flight per thread to cover HBM latency at the reduced
// occupancy. Per-t arithmetic is bit-identical to the verified kernel.
// ---------------------------------------------------------------------------
__launch_bounds__(1024, 4)
__global__ void contract_staged(const float* __restrict__ x,
                                const float2* __restrict__ noise,
                                const float4* __restrict__ params,
                                float* __restrict__ y, int N) {
    extern __shared__ float lds[];
    float* ly = lds;         // N floats: y-row accumulator
    float* lx = lds + N;     // N floats: x-row copy
    const int b = blockIdx.x;
    const int tid = threadIdx.x;
    const int nthr = blockDim.x;
    const int n4 = N >> 2;

    // zero ly and stage x-row (both vectorized, coalesced)
    float4* ly4 = (float4*)ly;
    vfloat4* lx4 = (vfloat4*)lx;
    const vfloat4* xb4 = (const vfloat4*)(x + (size_t)b * N);
    for (int i = tid; i < n4; i += nthr) {
        ly4[i] = make_float4(0.f, 0.f, 0.f, 0.f);
        lx4[i] = xb4[i];
    }
    __syncthreads();

    const float fN1 = (float)(N - 1);
    const vfloat4* nb4 = (const vfloat4*)(noise + (size_t)b * N);  // N/2 vecs
    const int npairs = N >> 1;

    for (int base = 0; base < npairs; base += 4 * nthr) {
        const int p0 = base + tid;
        const int p1 = p0 + nthr;
        const int p2 = p1 + nthr;
        const int p3 = p2 + nthr;

        // ---- issue all global loads first (address-independent) ----------
        vfloat4 nz0 = __builtin_nontemporal_load(&nb4[p0]);
        vfloat4 nz1 = __builtin_nontemporal_load(&nb4[p1]);
        vfloat4 nz2 = __builtin_nontemporal_load(&nb4[p2]);
        vfloat4 nz3 = __builtin_nontemporal_load(&nb4[p3]);
        float4 pa = params[2 * p0];
        float4 pb = params[2 * p0 + 1];
        float4 pc = params[2 * p1];
        float4 pd = params[2 * p1 + 1];
        float4 pe = params[2 * p2];
        float4 pf = params[2 * p2 + 1];
        float4 pg = params[2 * p3];
        float4 ph = params[2 * p3 + 1];

        // sample = mean + sigma*noise, deliberately UNFUSED (rounding must
        // match numpy's separate mul+add).
        float sA0 = __fadd_rn(pa.x, __fmul_rn(pa.z, nz0.x));
        float sA1 = __fadd_rn(pa.y, __fmul_rn(pa.z, nz0.y));
        float sB0 = __fadd_rn(pb.x, __fmul_rn(pb.z, nz0.z));
        float sB1 = __fadd_rn(pb.y, __fmul_rn(pb.z, nz0.w));
        float sC0 = __fadd_rn(pc.x, __fmul_rn(pc.z, nz1.x));
        float sC1 = __fadd_rn(pc.y, __fmul_rn(pc.z, nz1.y));
        float sD0 = __fadd_rn(pd.x, __fmul_rn(pd.z, nz1.z));
        float sD1 = __fadd_rn(pd.y, __fmul_rn(pd.z, nz1.w));
        float sE0 = __fadd_rn(pe.x, __fmul_rn(pe.z, nz2.x));
        float sE1 = __fadd_rn(pe.y, __fmul_rn(pe.z, nz2.y));
        float sF0 = __fadd_rn(pf.x, __fmul_rn(pf.z, nz2.z));
        float sF1 = __fadd_rn(pf.y, __fmul_rn(pf.z, nz2.w));
        float sG0 = __fadd_rn(pg.x, __fmul_rn(pg.z, nz3.x));
        float sG1 = __fadd_rn(pg.y, __fmul_rn(pg.z, nz3.y));
        float sH0 = __fadd_rn(ph.x, __fmul_rn(ph.z, nz3.z));
        float sH1 = __fadd_rn(ph.y, __fmul_rn(ph.z, nz3.w));

        // np.round = half-to-even = rintf; clamp in float, exact int cvt
        int rA = (int)fminf(fmaxf(rintf(sA0), 0.0f), fN1);
        int cA = (int)fminf(fmaxf(rintf(sA1), 0.0f), fN1);
        int rB = (int)fminf(fmaxf(rintf(sB0), 0.0f), fN1);
        int cB = (int)fminf(fmaxf(rintf(sB1), 0.0f), fN1);
        int rC = (int)fminf(fmaxf(rintf(sC0), 0.0f), fN1);
        int cC = (int)fminf(fmaxf(rintf(sC1), 0.0f), fN1);
        int rD = (int)fminf(fmaxf(rintf(sD0), 0.0f), fN1);
        int cD = (int)fminf(fmaxf(rintf(sD1), 0.0f), fN1);
        int rE = (int)fminf(fmaxf(rintf(sE0), 0.0f), fN1);
        int cE = (int)fminf(fmaxf(rintf(sE1), 0.0f), fN1);
        int rF = (int)fminf(fmaxf(rintf(sF0), 0.0f), fN1);
        int cF = (int)fminf(fmaxf(rintf(sF1), 0.0f), fN1);
        int rG = (int)fminf(fmaxf(rintf(sG0), 0.0f), fN1);
        int cG = (int)fminf(fmaxf(rintf(sG1), 0.0f), fN1);
        int rH = (int)fminf(fmaxf(rintf(sH0), 0.0f), fN1);
        int cH = (int)fminf(fmaxf(rintf(sH1), 0.0f), fN1);

        // gathers now hit LDS (cheap, no cache-line amplification)
        float xA = lx[cA];
        float xB = lx[cB];
        float xC = lx[cC];
        float xD = lx[cD];
        float xE = lx[cE];
        float xF = lx[cF];
        float xG = lx[cG];
        float xH = lx[cH];

        // fire-and-forget LDS atomics
        atomicAdd(&ly[rA], __fmul_rn(pa.w, xA));
        atomicAdd(&ly[rB], __fmul_rn(pb.w, xB));
        atomicAdd(&ly[rC], __fmul_rn(pc.w, xC));
        atomicAdd(&ly[rD], __fmul_rn(pd.w, xD));
        atomicAdd(&ly[rE], __fmul_rn(pe.w, xE));
        atomicAdd(&ly[rF], __fmul_rn(pf.w, xF));
        atomicAdd(&ly[rG], __fmul_rn(pg.w, xG));
        atomicAdd(&ly[rH], __fmul_rn(ph.w, xH));
    }
    __syncthreads();

    // coalesced nontemporal write-out of the full row
    const vfloat4* lv4 = (const vfloat4*)ly;
    vfloat4* yb4 = (vfloat4*)(y + (size_t)b * N);
    for (int i = tid; i < n4; i += nthr)
        __builtin_nontemporal_store(lv4[i], &yb4[i]);
}

// ---------------------------------------------------------------------------
// Fallback (round-2 verified kernel): used when ws/N/LDS constraints rule out
// the staged path.
// ---------------------------------------------------------------------------
template <bool INLINE_PARAMS>
__launch_bounds__(1024, 8)
__global__ void contract_kernel(const float* __restrict__ x,
                                const float2* __restrict__ noise,
                                const float4* __restrict__ params,
                                const float2* __restrict__ pmeans,
                                const float* __restrict__ psigmas,
                                const float* __restrict__ pvalues,
                                float* __restrict__ y, int N) {
    extern __shared__ float ly[];
    const int b = blockIdx.x;
    const int tid = threadIdx.x;
    const int nthr = blockDim.x;

    float4* ly4 = (float4*)ly;
    const int n4 = N >> 2;
    for (int i = tid; i < n4; i += nthr) ly4[i] = make_float4(0.f, 0.f, 0.f, 0.f);
    __syncthreads();

    const float* xb = x + (size_t)b * N;
    const float fN1 = (float)(N - 1);

    const float2* nb = noise + (size_t)b * N;
    for (int t = tid; t < N; t += nthr) {
        float m0, m1, sg, pv;
        if (INLINE_PARAMS) {
            float2 pm = pmeans[t];
            float scale = (float)(N - 1);
            m0 = __fmul_rn(__fdiv_rn(1.0f, __fadd_rn(1.0f, expf(-pm.x))), scale);
            m1 = __fmul_rn(__fdiv_rn(1.0f, __fadd_rn(1.0f, expf(-pm.y))), scale);
            float z  = __fadd_rn(psigmas[t], SIGMA_BOOST);
            float sp = __fadd_rn(fmaxf(z, 0.0f), log1pf(expf(-fabsf(z))));
            sg = __fmul_rn(__fadd_rn(sp, EPSILON), (float)N);
            pv = pvalues[t];
        } else {
            float4 p = params[t];
            m0 = p.x; m1 = p.y; sg = p.z; pv = p.w;
        }
        float2 nz = nb[t];
        float s0 = __fadd_rn(m0, __fmul_rn(sg, nz.x));
        float s1 = __fadd_rn(m1, __fmul_rn(sg, nz.y));
        int row = (int)fminf(fmaxf(rintf(s0), 0.0f), fN1);
        int col = (int)fminf(fmaxf(rintf(s1), 0.0f), fN1);
        float contrib = __fmul_rn(pv, xb[col]);
        atomicAdd(&ly[row], contrib);
    }
    __syncthreads();

    const vfloat4* lv4 = (const vfloat4*)ly;
    vfloat4* yb4 = (vfloat4*)(y + (size_t)b * N);
    for (int i = tid; i < n4; i += nthr)
        __builtin_nontemporal_store(lv4[i], &yb4[i]);
}

extern "C" void kernel_launch(void* const* d_in, const int* in_sizes, int n_in,
                              void* d_out, int out_size, void* d_ws, size_t ws_size,
                              hipStream_t stream) {
    const float*  x       = (const float*)d_in[0];
    const float2* noise   = (const float2*)d_in[1];
    const float2* pmeans  = (const float2*)d_in[2];
    const float*  psigmas = (const float*)d_in[3];
    const float*  pvalues = (const float*)d_in[4];
    float* y = (float*)d_out;

    const int N = in_sizes[3];          // psigmas is (N,)
    const int B = in_sizes[0] / N;      // x is (B,N)

    const size_t params_bytes = (size_t)N * sizeof(float4);
    const bool use_ws = (ws_size >= params_bytes) && (d_ws != nullptr);

    const int block = 1024;
    const size_t lds_acc   = (size_t)N * sizeof(float);      // 64 KB at N=16384
    const size_t lds_stage = 2 * lds_acc;                    // 128 KB

    bool staged_ok = false;
    if (use_ws && lds_stage <= 160 * 1024 &&
        ((N >> 1) % (4 * block)) == 0 && (N % 4) == 0) {
        // dynamic LDS >64 KB needs the opt-in attribute (gfx950 allows 160 KB)
        hipError_t e = hipFuncSetAttribute(
            reinterpret_cast<const void*>(contract_staged),
            hipFuncAttributeMaxDynamicSharedMemorySize, (int)lds_stage);
        staged_ok = (e == hipSuccess);
    }

    if (use_ws) {
        float4* params = (float4*)d_ws;
        params_kernel<<<(N + 255) / 256, 256, 0, stream>>>(pmeans, psigmas,
                                                           pvalues, params, N);
        if (staged_ok) {
            contract_staged<<<B, block, lds_stage, stream>>>(x, noise, params,
                                                             y, N);
        } else {
            contract_kernel<false><<<B, block, lds_acc, stream>>>(
                x, noise, params, nullptr, nullptr, nullptr, y, N);
        }
    } else {
        contract_kernel<true><<<B, block, lds_acc, stream>>>(
            x, noise, nullptr, pmeans, psigmas, pvalues, y, N);
    }
}

// Round 4
// 149.864 us; speedup vs baseline: 1.1396x; 1.1396x over previous
//
#include <hip/hip_runtime.h>
#include <math.h>

#define SIGMA_BOOST 2.0f
#define EPSILON 1e-6f

// native clang vector type — required for __builtin_nontemporal_load/store
typedef float vfloat4 __attribute__((ext_vector_type(4)));

// ---------------------------------------------------------------------------
// Pre-pass: per-t parameters -> float4 {mean_row, mean_col, sigma, pvalue}
//   mean  = sigmoid(pmean) * (N-1)
//   sigma = (softplus(psigma + SIGMA_BOOST) + EPS) * N
// ---------------------------------------------------------------------------
__global__ void params_kernel(const float2* __restrict__ pmeans,
                              const float* __restrict__ psigmas,
                              const float* __restrict__ pvalues,
                              float4* __restrict__ params, int N) {
    int t = blockIdx.x * blockDim.x + threadIdx.x;
    if (t >= N) return;
    float2 pm = pmeans[t];
    float scale = (float)(N - 1);
    float m0 = __fmul_rn(__fdiv_rn(1.0f, __fadd_rn(1.0f, expf(-pm.x))), scale);
    float m1 = __fmul_rn(__fdiv_rn(1.0f, __fadd_rn(1.0f, expf(-pm.y))), scale);
    float z  = __fadd_rn(psigmas[t], SIGMA_BOOST);
    float sp = __fadd_rn(fmaxf(z, 0.0f), log1pf(expf(-fabsf(z))));
    float sg = __fmul_rn(__fadd_rn(sp, EPSILON), (float)N);
    params[t] = make_float4(m0, m1, sg, pvalues[t]);
}

// ---------------------------------------------------------------------------
// Per-sample worker. KEY INSIGHT this round: sigma ~ 2.1*N, so ~80% of all
// rounded+clamped indices are exactly 0 or N-1. Same-address ds_add RMWs
// serialize lane-by-lane (~50 cyc/wave-instr) — that was the real cost of
// the previous kernels (invisible in SQ_LDS_BANK_CONFLICT). Peel the two
// degenerate targets into per-thread register accumulators (rows) and
// register broadcasts (cols); only the ~20% middle lanes touch LDS/global.
// Arithmetic through the index computation is bit-identical to the verified
// kernel (unfused mul+add, rintf, float clamp, exact int cvt).
// ---------------------------------------------------------------------------
__device__ __forceinline__ void process_sample(
        const float4 p, const float n0, const float n1,
        const float* __restrict__ xb, float* __restrict__ ly,
        const float x0, const float xE, const int iN1, const float fN1,
        float& acc0, float& accE) {
    float s0 = __fadd_rn(p.x, __fmul_rn(p.z, n0));
    float s1 = __fadd_rn(p.y, __fmul_rn(p.z, n1));
    int row = (int)fminf(fmaxf(rintf(s0), 0.0f), fN1);
    int col = (int)fminf(fmaxf(rintf(s1), 0.0f), fN1);
    float xv;
    if (col == 0)        xv = x0;     // ~40% of lanes: register broadcast
    else if (col == iN1) xv = xE;     // ~40% of lanes: register broadcast
    else                 xv = xb[col];// ~20% of lanes issue the gather
    float ctr = __fmul_rn(p.w, xv);
    if (row == 0)        acc0 = __fadd_rn(acc0, ctr);   // register accumulate
    else if (row == iN1) accE = __fadd_rn(accE, ctr);   // register accumulate
    else                 atomicAdd(&ly[row], ctr);      // sparse, ~no collisions
}

// ---------------------------------------------------------------------------
// One block per batch row. 64 KB LDS y-row accumulator; 2 blocks/CU
// (32 waves/CU). 4-t unrolled main loop (round-2 verified structure) with
// the degenerate-index peeling above. Wave-level shfl reduction folds the
// register accumulators into ly[0]/ly[N-1] once per wave at the end.
// ---------------------------------------------------------------------------
template <bool INLINE_PARAMS>
__launch_bounds__(1024, 8)
__global__ void contract_kernel(const float* __restrict__ x,
                                const float2* __restrict__ noise,
                                const float4* __restrict__ params,
                                const float2* __restrict__ pmeans,
                                const float* __restrict__ psigmas,
                                const float* __restrict__ pvalues,
                                float* __restrict__ y, int N) {
    extern __shared__ float ly[];
    const int b = blockIdx.x;
    const int tid = threadIdx.x;
    const int nthr = blockDim.x;

    // zero LDS accumulator (vectorized)
    float4* ly4 = (float4*)ly;
    const int n4 = N >> 2;
    for (int i = tid; i < n4; i += nthr) ly4[i] = make_float4(0.f, 0.f, 0.f, 0.f);
    __syncthreads();

    const float* xb = x + (size_t)b * N;
    const float fN1 = (float)(N - 1);
    const int iN1 = N - 1;
    const float x0 = xb[0];
    const float xE = xb[iN1];
    float acc0 = 0.0f, accE = 0.0f;

    if (!INLINE_PARAMS && ((N >> 1) % (2 * nthr)) == 0) {
        // ---- fast path: 4 t's (2 x 16B noise loads) per step ---------------
        const vfloat4* nb4 = (const vfloat4*)(noise + (size_t)b * N);  // N/2 vecs
        const int npairs = N >> 1;
        for (int base = 0; base < npairs; base += 2 * nthr) {
            const int p0 = base + tid;
            const int p1 = p0 + nthr;
            // issue all coalesced loads first (address-independent)
            vfloat4 nz0 = __builtin_nontemporal_load(&nb4[p0]);
            vfloat4 nz1 = __builtin_nontemporal_load(&nb4[p1]);
            float4 pa = params[2 * p0];
            float4 pb = params[2 * p0 + 1];
            float4 pc = params[2 * p1];
            float4 pd = params[2 * p1 + 1];

            process_sample(pa, nz0.x, nz0.y, xb, ly, x0, xE, iN1, fN1, acc0, accE);
            process_sample(pb, nz0.z, nz0.w, xb, ly, x0, xE, iN1, fN1, acc0, accE);
            process_sample(pc, nz1.x, nz1.y, xb, ly, x0, xE, iN1, fN1, acc0, accE);
            process_sample(pd, nz1.z, nz1.w, xb, ly, x0, xE, iN1, fN1, acc0, accE);
        }
    } else {
        // ---- generic / inline-params fallback ------------------------------
        const float2* nb = noise + (size_t)b * N;
        for (int t = tid; t < N; t += nthr) {
            float4 p;
            if (INLINE_PARAMS) {
                float2 pm = pmeans[t];
                float scale = (float)(N - 1);
                p.x = __fmul_rn(__fdiv_rn(1.0f, __fadd_rn(1.0f, expf(-pm.x))), scale);
                p.y = __fmul_rn(__fdiv_rn(1.0f, __fadd_rn(1.0f, expf(-pm.y))), scale);
                float z  = __fadd_rn(psigmas[t], SIGMA_BOOST);
                float sp = __fadd_rn(fmaxf(z, 0.0f), log1pf(expf(-fabsf(z))));
                p.z = __fmul_rn(__fadd_rn(sp, EPSILON), (float)N);
                p.w = pvalues[t];
            } else {
                p = params[t];
            }
            float2 nz = nb[t];
            process_sample(p, nz.x, nz.y, xb, ly, x0, xE, iN1, fN1, acc0, accE);
        }
    }

    // fold register accumulators: wave shfl-reduce, one atomic per wave
    for (int off = 32; off > 0; off >>= 1) {
        acc0 = __fadd_rn(acc0, __shfl_down(acc0, off, 64));
        accE = __fadd_rn(accE, __shfl_down(accE, off, 64));
    }
    if ((tid & 63) == 0) {
        atomicAdd(&ly[0], acc0);
        atomicAdd(&ly[iN1], accE);
    }
    __syncthreads();

    // coalesced nontemporal write-out of the full row
    const vfloat4* lv4 = (const vfloat4*)ly;
    vfloat4* yb4 = (vfloat4*)(y + (size_t)b * N);
    for (int i = tid; i < n4; i += nthr)
        __builtin_nontemporal_store(lv4[i], &yb4[i]);
}

extern "C" void kernel_launch(void* const* d_in, const int* in_sizes, int n_in,
                              void* d_out, int out_size, void* d_ws, size_t ws_size,
                              hipStream_t stream) {
    const float*  x       = (const float*)d_in[0];
    const float2* noise   = (const float2*)d_in[1];
    const float2* pmeans  = (const float2*)d_in[2];
    const float*  psigmas = (const float*)d_in[3];
    const float*  pvalues = (const float*)d_in[4];
    float* y = (float*)d_out;

    const int N = in_sizes[3];          // psigmas is (N,)
    const int B = in_sizes[0] / N;      // x is (B,N)

    const size_t params_bytes = (size_t)N * sizeof(float4);
    const bool use_ws = (ws_size >= params_bytes) && (d_ws != nullptr);

    const int block = 1024;
    const size_t lds_bytes = (size_t)N * sizeof(float);  // 64 KB at N=16384

    if (use_ws) {
        float4* params = (float4*)d_ws;
        params_kernel<<<(N + 255) / 256, 256, 0, stream>>>(pmeans, psigmas,
                                                           pvalues, params, N);
        contract_kernel<false><<<B, block, lds_bytes, stream>>>(
            x, noise, params, nullptr, nullptr, nullptr, y, N);
    } else {
        contract_kernel<true><<<B, block, lds_bytes, stream>>>(
            x, noise, nullptr, pmeans, psigmas, pvalues, y, N);
    }
}